// Round 13
// baseline (41.804 us; speedup 1.0000x reference)
//
#include <hip/hip_runtime.h>

// input x: (B=256,T=600,J=25,C=3) f32; x[b,tt,n*5+p,c] = in[(b*600+tt)*75 + n*15 + p*3 + c]
// output: (B,5,1800,4,4) f32, windows concatenated along tout (g in {0,1,2}: tout=g*600+tt).
//
// R13: software-pipelined stage. Block = (b, 200-tt segment) = 4 chunks of 50 tt.
// raw LDS double-buffered; chunk c+1's global loads are issued into registers
// BEFORE chunk c's 3 compute+store batches, ds_written after them (T14 split) --
// read latency hides under compute/store. 768 blocks = exactly 3/CU co-resident.
// Keeps R12's nontemporal lane-contiguous cooperative stores + lgkm-only barriers.

#define T_ 600
#define RAWSZ (52 * 75)   // 3900 floats per chunk buffer (50 rows + halo)

typedef float fx4 __attribute__((ext_vector_type(4)));

// LDS-only barrier: order LDS ops (lgkmcnt) but let global stores stay in flight.
#define BAR_LDS() do { asm volatile("s_waitcnt lgkmcnt(0)" ::: "memory"); \
                       __builtin_amdgcn_s_barrier(); } while (0)

__global__ __launch_bounds__(256) void gauss_agg_kernel(const float* __restrict__ x,
                                                        float* __restrict__ out) {
    __shared__ float raw[2][RAWSZ];      // 31.2 KB
    __shared__ float4 obuf[256 * 5];     // 20 KB; 80B/slot stride avoids bank aliasing

    int blk = blockIdx.x;                // 768 = 256 b * 3 segments
    int seg = blk % 3;
    int bb  = blk / 3;
    int tid = (int)threadIdx.x;

    const float* xb = x + (size_t)bb * T_ * 75;
    fx4* outf4 = reinterpret_cast<fx4*>(out);
    const float w5[5] = {4.f, 2.f, 3.f, 2.f, 4.f};

    float v[16];
    int cur = 0;

    // ---- prologue: stage chunk 0 of this segment ----
    {
        int tc = seg * 200;
        int start = (tc == 0) ? 0 : tc - 1;
        int end = tc + 51; if (end > T_) end = T_;
        int tot = (end - start) * 75;
        const float* src = xb + (size_t)start * 75;
        #pragma unroll
        for (int i = 0; i < 16; ++i) { int e = i * 256 + tid; v[i] = (e < tot) ? src[e] : 0.f; }
        #pragma unroll
        for (int i = 0; i < 16; ++i) { int e = i * 256 + tid; if (e < tot) raw[0][e] = v[i]; }
        BAR_LDS();
    }

    for (int c = 0; c < 4; ++c) {
        int tc  = seg * 200 + c * 50;
        int ofs = (tc == 0) ? 0 : 1;      // local row of tt = (tt - tc) + ofs

        // ---- issue next chunk's loads NOW (complete during compute/store) ----
        bool havnext = (c < 3);
        if (havnext) {
            int tn = tc + 50;
            int start = tn - 1;           // tn >= 50 so no clamp needed
            int end = tn + 51; if (end > T_) end = T_;
            int tot = (end - start) * 75;
            const float* src = xb + (size_t)start * 75;
            #pragma unroll
            for (int i = 0; i < 16; ++i) { int e = i * 256 + tid; v[i] = (e < tot) ? src[e] : 0.f; }
        }

        // ---- 3 batches of 256 slots (750 = 5n x 3w x 50tl) ----
        for (int m = 0; m < 3; ++m) {
            int s = m * 256 + tid;
            if (s < 750) {
                int n  = s / 150;
                int q  = s - n * 150;
                int w  = q / 50;
                int tl = q - w * 50;
                int tt = tc + tl;
                int li = tl + ofs;

                bool boundary;
                if (w == 0)      boundary = (tt == 0) || (tt == 599);
                else if (w == 1) boundary = (tt == 0) || (tt == 299) || (tt == 300) || (tt == 599);
                else             boundary = (tt == 0) || (tt == 199) || (tt == 200) ||
                                            (tt == 399) || (tt == 400) || (tt == 599);

                const float* rc = &raw[cur][li * 75 + n * 15];

                float s0=0.f,s1=0.f,s2=0.f, m0=0.f,m1=0.f,m2=0.f;
                float A00=0.f,A01=0.f,A02=0.f,A11=0.f,A12=0.f,A22=0.f;
                #pragma unroll
                for (int p = 0; p < 5; ++p) {
                    float a = rc[p*3+0], cc = rc[p*3+1], d = rc[p*3+2];
                    s0 += a; s1 += cc; s2 += d;
                    m0 += w5[p]*a; m1 += w5[p]*cc; m2 += w5[p]*d;
                    A00 += a*a; A01 += a*cc; A02 += a*d;
                    A11 += cc*cc; A12 += cc*d; A22 += d*d;
                }
                float mu0 = m0*(1.f/15.f), mu1 = m1*(1.f/15.f), mu2 = m2*(1.f/15.f);

                float inv = 0.2f;
                if (!boundary) {
                    #pragma unroll
                    for (int dstep = 0; dstep < 2; ++dstep) {
                        const float* rn = rc + (dstep ? 75 : -75);
                        #pragma unroll
                        for (int p = 0; p < 5; ++p) {
                            float a = rn[p*3+0], cc = rn[p*3+1], d = rn[p*3+2];
                            s0 += a; s1 += cc; s2 += d;
                            A00 += a*a; A01 += a*cc; A02 += a*d;
                            A11 += cc*cc; A12 += cc*d; A22 += d*d;
                        }
                    }
                    inv = 1.f/15.f;
                }

                float mb0 = s0*inv, mb1 = s1*inv, mb2 = s2*inv;
                float e00 = A00*inv - 2.f*mu0*mb0 + 2.f*mu0*mu0;
                float e01 = A01*inv - mu0*mb1 - mb0*mu1 + 2.f*mu0*mu1;
                float e02 = A02*inv - mu0*mb2 - mb0*mu2 + 2.f*mu0*mu2;
                float e11 = A11*inv - 2.f*mu1*mb1 + 2.f*mu1*mu1;
                float e12 = A12*inv - mu1*mb2 - mb1*mu2 + 2.f*mu1*mu2;
                float e22 = A22*inv - 2.f*mu2*mb2 + 2.f*mu2*mu2;

                int base = tid * 5;
                obuf[base + 0] = make_float4(e00, e01, e02, mu0);
                obuf[base + 1] = make_float4(e01, e11, e12, mu1);
                obuf[base + 2] = make_float4(e02, e12, e22, mu2);
                obuf[base + 3] = make_float4(mu0, mu1, mu2, 1.f);
            }
            BAR_LDS();

            // ---- cooperative lane-contiguous nontemporal store ----
            int nslots  = 750 - m * 256; if (nslots > 256) nslots = 256;
            int npieces = nslots * 4;
            #pragma unroll
            for (int k2 = 0; k2 < 4; ++k2) {
                int f = k2 * 256 + tid;
                if (f < npieces) {
                    int sl = f >> 2, pc = f & 3;
                    int s2 = m * 256 + sl;
                    int n  = s2 / 150;
                    int q  = s2 - n * 150;
                    int w  = q / 50;
                    int tl = q - w * 50;
                    int tt = tc + tl;
                    size_t o = ((size_t)(bb * 5 + n) * 1800 + w * 600 + tt) * 4 + pc;
                    float4 vv = obuf[sl * 5 + pc];
                    fx4 nv; nv.x = vv.x; nv.y = vv.y; nv.z = vv.z; nv.w = vv.w;
                    __builtin_nontemporal_store(nv, &outf4[o]);
                }
            }
            BAR_LDS();
        }

        // ---- commit next chunk's rows to the other raw buffer ----
        if (havnext) {
            int tn = tc + 50;
            int start = tn - 1;
            int end = tn + 51; if (end > T_) end = T_;
            int tot = (end - start) * 75;
            #pragma unroll
            for (int i = 0; i < 16; ++i) { int e = i * 256 + tid; if (e < tot) raw[cur ^ 1][e] = v[i]; }
            BAR_LDS();
            cur ^= 1;
        }
    }
}

extern "C" void kernel_launch(void* const* d_in, const int* in_sizes, int n_in,
                              void* d_out, int out_size, void* d_ws, size_t ws_size,
                              hipStream_t stream) {
    const float* x = (const float*)d_in[0];
    float* out = (float*)d_out;
    gauss_agg_kernel<<<768, 256, 0, stream>>>(x, out);
}

// Round 14
// 40.191 us; speedup vs baseline: 1.0401x; 1.0401x over previous
//
#include <hip/hip_runtime.h>

// input x: (B=256,T=600,J=25,C=3) f32; x[b,tt,n*5+p,c] = in[(b*600+tt)*75 + n*15 + p*3 + c]
// output: (B,5,1800,4,4) f32, windows concatenated along tout.
//
// R14 = R12 (41.2us: LDS stage -> slot-per-thread compute -> bank-padded obuf ->
// lane-contiguous nontemporal coop store; lgkm-only barriers) + VECTORIZED stage:
// main 100 rows (1875 float4, 16B-aligned since (b*600+tc)*300 % 16 == 0) staged as
// dwordx4 -> ds_write_b128; the two halo rows (tc-1, tc+100) staged scalar into a
// tail region raw[7500..7650). Stage instrs/thread: 60 -> ~17.

#define T_ 600
#define CH_ 100
#define NCH_ 6

typedef float fx4 __attribute__((ext_vector_type(4)));

// LDS-only barrier: order LDS ops (lgkmcnt) but let global stores stay in flight.
#define BAR_LDS() do { asm volatile("s_waitcnt lgkmcnt(0)" ::: "memory"); \
                       __builtin_amdgcn_s_barrier(); } while (0)

__global__ __launch_bounds__(256) void gauss_agg_kernel(const float* __restrict__ x,
                                                        float* __restrict__ out) {
    // raw layout: [0,7500) = rows tc..tc+99 (75 floats each); [7500,7575) = row tc-1;
    // [7575,7650) = row tc+100. 30.6 KB. obuf: 20 KB (80B/slot stride).
    __shared__ float raw[7650];
    __shared__ float4 obuf[256 * 5];

    int blk = blockIdx.x;
    int ch  = blk % NCH_;
    int b   = blk / NCH_;
    int tc  = ch * CH_;
    int tid = (int)threadIdx.x;

    // ---- stage: main chunk vectorized, halo rows scalar ----
    const float4* srcv = reinterpret_cast<const float4*>(x + ((size_t)b * T_ + tc) * 75);
    float4* rawv = reinterpret_cast<float4*>(raw);
    #pragma unroll
    for (int i = 0; i < 8; ++i) {
        int e = i * 256 + tid;
        if (e < 1875) rawv[e] = srcv[e];
    }
    if (tid < 150) {
        int rp  = (tid < 75) ? (tc > 0 ? tc - 1 : 0)
                             : (tc + 100 < T_ ? tc + 100 : T_ - 1);
        int col = (tid < 75) ? tid : tid - 75;
        raw[7500 + tid] = x[((size_t)b * T_ + rp) * 75 + col];
    }
    BAR_LDS();

    const float w5[5] = {4.f, 2.f, 3.f, 2.f, 4.f};
    fx4* outf4 = reinterpret_cast<fx4*>(out);

    // ---- 6 batches of 256 slots (1500 = 5n x 3w x 100tl) ----
    for (int m = 0; m < 6; ++m) {
        int s = m * 256 + tid;
        if (s < 1500) {
            int n  = s / 300;
            int q  = s - n * 300;
            int w  = q / 100;
            int tl = q - w * 100;
            int tt = tc + tl;

            bool boundary;
            if (w == 0)      boundary = (tt == 0) || (tt == 599);
            else if (w == 1) boundary = (tt == 0) || (tt == 299) || (tt == 300) || (tt == 599);
            else             boundary = (tt == 0) || (tt == 199) || (tt == 200) ||
                                        (tt == 399) || (tt == 400) || (tt == 599);

            int midoff = tl * 75 + n * 15;
            const float* rc = &raw[midoff];

            float s0=0.f,s1=0.f,s2=0.f, m0=0.f,m1=0.f,m2=0.f;
            float A00=0.f,A01=0.f,A02=0.f,A11=0.f,A12=0.f,A22=0.f;
            #pragma unroll
            for (int p = 0; p < 5; ++p) {
                float a = rc[p*3+0], c = rc[p*3+1], d = rc[p*3+2];
                s0 += a; s1 += c; s2 += d;
                m0 += w5[p]*a; m1 += w5[p]*c; m2 += w5[p]*d;
                A00 += a*a; A01 += a*c; A02 += a*d;
                A11 += c*c; A12 += c*d; A22 += d*d;
            }
            float mu0 = m0*(1.f/15.f), mu1 = m1*(1.f/15.f), mu2 = m2*(1.f/15.f);

            float inv = 0.2f;
            if (!boundary) {
                // neighbor rows: halo tail regions at chunk edges (always staged;
                // global-edge cases are boundary slots and never reach here)
                const float* rp_ = &raw[(tl == 0)  ? 7500 + n * 15 : midoff - 75];
                const float* rn_ = &raw[(tl == 99) ? 7575 + n * 15 : midoff + 75];
                #pragma unroll
                for (int dstep = 0; dstep < 2; ++dstep) {
                    const float* rn = dstep ? rn_ : rp_;
                    #pragma unroll
                    for (int p = 0; p < 5; ++p) {
                        float a = rn[p*3+0], c = rn[p*3+1], d = rn[p*3+2];
                        s0 += a; s1 += c; s2 += d;
                        A00 += a*a; A01 += a*c; A02 += a*d;
                        A11 += c*c; A12 += c*d; A22 += d*d;
                    }
                }
                inv = 1.f/15.f;
            }

            float mb0 = s0*inv, mb1 = s1*inv, mb2 = s2*inv;
            float e00 = A00*inv - 2.f*mu0*mb0 + 2.f*mu0*mu0;
            float e01 = A01*inv - mu0*mb1 - mb0*mu1 + 2.f*mu0*mu1;
            float e02 = A02*inv - mu0*mb2 - mb0*mu2 + 2.f*mu0*mu2;
            float e11 = A11*inv - 2.f*mu1*mb1 + 2.f*mu1*mu1;
            float e12 = A12*inv - mu1*mb2 - mb1*mu2 + 2.f*mu1*mu2;
            float e22 = A22*inv - 2.f*mu2*mb2 + 2.f*mu2*mu2;

            int base = tid * 5;
            obuf[base + 0] = make_float4(e00, e01, e02, mu0);
            obuf[base + 1] = make_float4(e01, e11, e12, mu1);
            obuf[base + 2] = make_float4(e02, e12, e22, mu2);
            obuf[base + 3] = make_float4(mu0, mu1, mu2, 1.f);
        }
        BAR_LDS();

        // ---- cooperative lane-contiguous NONTEMPORAL store of this batch ----
        int nslots  = (1500 - m * 256 < 256) ? (1500 - m * 256) : 256;
        int npieces = nslots * 4;
        #pragma unroll
        for (int k = 0; k < 4; ++k) {
            int f = k * 256 + tid;
            if (f < npieces) {
                int sl = f >> 2, pc = f & 3;
                int s2 = m * 256 + sl;
                int n  = s2 / 300;
                int q  = s2 - n * 300;
                int w  = q / 100;
                int tl = q - w * 100;
                int tt = tc + tl;
                size_t o = ((size_t)(b * 5 + n) * 1800 + w * 600 + tt) * 4 + pc;
                float4 v = obuf[sl * 5 + pc];
                fx4 nv; nv.x = v.x; nv.y = v.y; nv.z = v.z; nv.w = v.w;
                __builtin_nontemporal_store(nv, &outf4[o]);
            }
        }
        BAR_LDS();
    }
}

extern "C" void kernel_launch(void* const* d_in, const int* in_sizes, int n_in,
                              void* d_out, int out_size, void* d_ws, size_t ws_size,
                              hipStream_t stream) {
    const float* x = (const float*)d_in[0];
    float* out = (float*)d_out;
    gauss_agg_kernel<<<256 * NCH_, 256, 0, stream>>>(x, out);
}

// Round 15
// 37.891 us; speedup vs baseline: 1.1033x; 1.0607x over previous
//
#include <hip/hip_runtime.h>

// input x: (B=256,T=600,J=25,C=3) f32; x[b,tt,n*5+p,c] = in[(b*600+tt)*75 + n*15 + p*3 + c]
// output: (B,5,1800,4,4) f32, 3 window groups g: tout = g*600+tt.
//
// R15: DEDUP compute. Interior results are w-independent; center-only (boundary)
// results are also w-independent. Per 50-tt chunk the unique work = 250 interior
// slots (5n x 50tl) + <=5 center-variant slots (the single window-boundary tt a
// 50-chunk can contain) = 255 -> ONE compute batch, 2 barriers/block total.
// Store = 12-iter lane-contiguous nontemporal sweep (R7/R12 proven pattern),
// reading the deduped obuf 3x. Stage = R14-style aligned b128 (head/vec/tail).

#define T_ 600
#define CH_ 50
#define NCH_ 12

typedef float fx4 __attribute__((ext_vector_type(4)));

// LDS-only barrier: order LDS ops but let global stores stay in flight.
#define BAR_LDS() do { asm volatile("s_waitcnt lgkmcnt(0)" ::: "memory"); \
                       __builtin_amdgcn_s_barrier(); } while (0)

__global__ __launch_bounds__(256) void gauss_agg_kernel(const float* __restrict__ x,
                                                        float* __restrict__ out) {
    __shared__ float raw[3908];        // off(<=3) + 52 rows * 75 floats, 15.6 KB
    __shared__ float4 obuf[256 * 5];   // 20 KB; 80B/slot stride avoids bank aliasing

    int blk = blockIdx.x;
    int ch  = blk % NCH_;
    int b   = blk / NCH_;
    int tc  = ch * CH_;
    int tid = (int)threadIdx.x;

    // the (at most one) window-boundary tt inside this chunk
    int vtt = -1;
    switch (ch) {
        case 0:  vtt = 0;   break;
        case 3:  vtt = 199; break;
        case 4:  vtt = 200; break;
        case 5:  vtt = 299; break;
        case 6:  vtt = 300; break;
        case 7:  vtt = 399; break;
        case 8:  vtt = 400; break;
        case 11: vtt = 599; break;
        default: break;
    }

    int start = (tc == 0) ? 0 : tc - 1;
    int end   = tc + CH_ + 1; if (end > T_) end = T_;
    int nrows = end - start;
    int ofs   = tc - start;            // 0 or 1
    int tot   = nrows * 75;
    size_t gbase = (size_t)b * 45000 + (size_t)start * 75;

    // ---- stage (linear layout, aligned b128 bulk): lds[off + c4] = x[gbase + c4] ----
    int head = (int)((4 - (gbase & 3)) & 3);   // floats until global 16B alignment
    int off  = (4 - head) & 3;                 // lds shift so bulk writes are 16B-aligned
    {
        if (head > tot) head = tot;
        int nv   = (tot - head) >> 2;
        int tail = tot - head - nv * 4;
        if (tid < head) raw[off + tid] = x[gbase + tid];
        const float4* srcv = reinterpret_cast<const float4*>(x + gbase + head);
        float4* rawv = reinterpret_cast<float4*>(&raw[off + head]);
        #pragma unroll
        for (int i = 0; i < 4; ++i) {
            int e = i * 256 + tid;
            if (e < nv) rawv[e] = srcv[e];
        }
        if (tid < tail) raw[off + head + 4 * nv + tid] = x[gbase + head + 4 * nv + tid];
    }
    BAR_LDS();

    // ---- compute: ONE batch of 255 unique slots ----
    {
        bool isvar = (tid >= 250);
        int n, tt;
        if (!isvar) { n = tid / 50; tt = tc + (tid - n * 50); }
        else        { int k = tid - 250; n = (k > 4) ? 4 : k; tt = (vtt < 0) ? tc : vtt; }
        int li = tt - tc + ofs;
        int lp = li - 1; if (lp < 0) lp = 0;   // only tc==0,tt==0 (result unused)
        int ln = li + 1;                        // may read junk for tt==599 (unused)

        const float w5[5] = {4.f, 2.f, 3.f, 2.f, 4.f};
        const float* rc = &raw[off + li * 75 + n * 15];

        float s0=0.f,s1=0.f,s2=0.f, m0=0.f,m1=0.f,m2=0.f;
        float A00=0.f,A01=0.f,A02=0.f,A11=0.f,A12=0.f,A22=0.f;
        #pragma unroll
        for (int p = 0; p < 5; ++p) {
            float a = rc[p*3+0], c = rc[p*3+1], d = rc[p*3+2];
            s0 += a; s1 += c; s2 += d;
            m0 += w5[p]*a; m1 += w5[p]*c; m2 += w5[p]*d;
            A00 += a*a; A01 += a*c; A02 += a*d;
            A11 += c*c; A12 += c*d; A22 += d*d;
        }
        float mu0 = m0*(1.f/15.f), mu1 = m1*(1.f/15.f), mu2 = m2*(1.f/15.f);

        float inv = 0.2f;
        if (!isvar) {
            const float* r0 = &raw[off + lp * 75 + n * 15];
            const float* r1 = &raw[off + ln * 75 + n * 15];
            #pragma unroll
            for (int dstep = 0; dstep < 2; ++dstep) {
                const float* rn = dstep ? r1 : r0;
                #pragma unroll
                for (int p = 0; p < 5; ++p) {
                    float a = rn[p*3+0], c = rn[p*3+1], d = rn[p*3+2];
                    s0 += a; s1 += c; s2 += d;
                    A00 += a*a; A01 += a*c; A02 += a*d;
                    A11 += c*c; A12 += c*d; A22 += d*d;
                }
            }
            inv = 1.f/15.f;
        }

        float mb0 = s0*inv, mb1 = s1*inv, mb2 = s2*inv;
        float e00 = A00*inv - 2.f*mu0*mb0 + 2.f*mu0*mu0;
        float e01 = A01*inv - mu0*mb1 - mb0*mu1 + 2.f*mu0*mu1;
        float e02 = A02*inv - mu0*mb2 - mb0*mu2 + 2.f*mu0*mu2;
        float e11 = A11*inv - 2.f*mu1*mb1 + 2.f*mu1*mu1;
        float e12 = A12*inv - mu1*mb2 - mb1*mu2 + 2.f*mu1*mu2;
        float e22 = A22*inv - 2.f*mu2*mb2 + 2.f*mu2*mu2;

        int base = tid * 5;
        obuf[base + 0] = make_float4(e00, e01, e02, mu0);
        obuf[base + 1] = make_float4(e01, e11, e12, mu1);
        obuf[base + 2] = make_float4(e02, e12, e22, mu2);
        obuf[base + 3] = make_float4(mu0, mu1, mu2, 1.f);
    }
    BAR_LDS();

    // ---- store: 750 output slots x 4 pieces, lane-contiguous nontemporal ----
    fx4* outf4 = reinterpret_cast<fx4*>(out);
    #pragma unroll
    for (int k = 0; k < 12; ++k) {
        int f = k * 256 + tid;
        if (f < 3000) {
            int sl = f >> 2, pc = f & 3;
            int n  = sl / 150;
            int q  = sl - n * 150;
            int w  = q / 50;
            int tl = q - w * 50;
            int tt = tc + tl;
            bool bd;
            if (w == 0)      bd = (tt == 0) || (tt == 599);
            else if (w == 1) { int r = tt % 300; bd = (r == 0) || (r == 299); }
            else             { int r = tt % 200; bd = (r == 0) || (r == 199); }
            int oi = bd ? (250 + n) : sl % 250;     // interior: n*50+tl == sl-n*150+n*50... see below
            // interior obuf index is n*50+tl:
            if (!bd) oi = n * 50 + tl;
            size_t o = ((size_t)(b * 5 + n) * 1800 + w * 600 + tt) * 4 + pc;
            float4 v = obuf[oi * 5 + pc];
            fx4 nv; nv.x = v.x; nv.y = v.y; nv.z = v.z; nv.w = v.w;
            __builtin_nontemporal_store(nv, &outf4[o]);
        }
    }
}

extern "C" void kernel_launch(void* const* d_in, const int* in_sizes, int n_in,
                              void* d_out, int out_size, void* d_ws, size_t ws_size,
                              hipStream_t stream) {
    const float* x = (const float*)d_in[0];
    float* out = (float*)d_out;
    gauss_agg_kernel<<<256 * NCH_, 256, 0, stream>>>(x, out);
}